// Round 9
// baseline (1358.227 us; speedup 1.0000x reference)
//
#include <hip/hip_runtime.h>
#include <math.h>

#define CMAX 8
#define KMAX 16
#define TPB 256
#define BNMAX 1024
#define NSTEP 50

struct P {
  const float* fs; const int* ys; const float* fq;
  int S, Q, D, BN, NMAX;
  float* proto;
  float* G;
  float* cosq;
  int* cls; int* scount; int* qcount; int* qidx; int* kq;
  float* thr;
  int* rowcnt; int* rowoff; int* paircnt; int* basev;
  int* meta;     // [0]=C [1]=n [2]=k
  int* uv;
  float* rn2;
  int* cand;     // int4 per row: u,v,bits(rn2),0
  int* nbrs; float* dnb; float* wgt; float* sigma;
  int* indeg; int* inoff; int* cursor;
  int* insrcU; float* inwU; int* indst;
  int2* inedge;  // packed rank-sorted transpose edges (src, w-bits)
  unsigned* cosk;
  unsigned* gmaxu;
  float* amat; float* dinv; float* dmin; float* scalev;
  float* ybufs;  // [NSTEP+1][NMAX][CMAX]
  float* meddenom;
  int* outp;
};

__device__ inline unsigned f2key(float f){
  unsigned b=__float_as_uint(f);
  return (b&0x80000000u)? ~b : (b|0x80000000u);
}
__device__ inline float key2f(unsigned k){
  unsigned b=(k&0x80000000u)? (k^0x80000000u) : ~k;
  return __uint_as_float(b);
}
__device__ inline unsigned long long shfl_xor_u64(unsigned long long v,int m){
  unsigned lo=(unsigned)v, hi=(unsigned)(v>>32);
  lo=__shfl_xor(lo,m,64); hi=__shfl_xor(hi,m,64);
  return (((unsigned long long)hi)<<32)|lo;
}

// ---------- setup ----------
__global__ void k_init(P p){
  if (threadIdx.x==0){
    int labs[CMAX]; int cnt[CMAX]; int C=0;
    for (int s=0;s<p.S;s++){
      int l=p.ys[s]; int f=-1;
      for(int c=0;c<C;c++) if(labs[c]==l){f=c;break;}
      if(f<0){ if(C<CMAX){labs[C]=l;cnt[C]=1;C++;} }
      else cnt[f]++;
    }
    for(int a=0;a<C;a++)for(int b=a+1;b<C;b++)
      if(labs[b]<labs[a]){int t=labs[a];labs[a]=labs[b];labs[b]=t;
                          t=cnt[a];cnt[a]=cnt[b];cnt[b]=t;}
    for(int c=0;c<C;c++){p.cls[c]=labs[c];p.scount[c]=cnt[c];}
    p.meta[0]=C;
  }
}

__global__ void k_proto(P p){
  int c=blockIdx.x; int C=p.meta[0];
  for(int d=threadIdx.x; d<p.D; d+=blockDim.x){
    float s=0.f;
    if(c<C){
      int lab=p.cls[c];
      for(int j=0;j<p.S;j++) if(p.ys[j]==lab) s+=p.fs[(size_t)j*p.D+d];
      s/= (float)p.scount[c];
    }
    p.proto[(size_t)c*p.D+d]=s;
  }
}

__global__ void k_gram(P p){
  __shared__ float arow[1024];
  int a=blockIdx.x;
  const float* ra = (a<p.Q)? p.fq + (size_t)a*p.D : p.proto + (size_t)(a-p.Q)*p.D;
  const float* A = ra;
  if(p.D<=1024){
    for(int d=threadIdx.x; d<p.D; d+=blockDim.x) arow[d]=ra[d];
    __syncthreads();
    A=(const float*)arow;
  }
  int D4=p.D>>2; int Dt=D4<<2;
  for(int b=threadIdx.x; b<p.BN; b+=blockDim.x){
    const float* rb=(b<p.Q)? p.fq+(size_t)b*p.D : p.proto+(size_t)(b-p.Q)*p.D;
    const float4* a4=(const float4*)A;
    const float4* b4=(const float4*)rb;
    float s=0.f;
    #pragma unroll 4
    for(int d=0;d<D4;d++){
      float4 x=a4[d], y=b4[d];
      s += x.x*y.x + x.y*y.y + x.z*y.z + x.w*y.w;
    }
    for(int d=Dt;d<p.D;d++) s += A[d]*rb[d];
    p.G[(size_t)a*p.BN+b]=s;
  }
}

__global__ void k_cos(P p){
  int t=blockIdx.x*blockDim.x+threadIdx.x;
  if(t>=p.Q*p.Q)return;
  int i=t/p.Q, j=t%p.Q;
  p.cosq[t]=p.G[(size_t)i*p.BN+j]/(sqrtf(p.G[(size_t)i*p.BN+i])*sqrtf(p.G[(size_t)j*p.BN+j]));
}

// ---------- per-class index lists + kq (ybt computed inline) ----------
__global__ void k_qidx(P p){
  int c=blockIdx.x; int C=p.meta[0];
  int lane=threadIdx.x;
  if(c>=C){ if(lane==0){p.qcount[c]=0;p.kq[c]=0;} return; }
  int base=0;
  for(int q0=0;q0<p.Q;q0+=64){
    int q=q0+lane;
    bool in=false;
    if(q<p.Q){
      float gq=p.G[(size_t)q*p.BN+q];
      float best=INFINITY; int bc=0;
      for(int cc=0;cc<C;cc++){
        int pc=p.Q+cc;
        float d2=fmaxf(gq+p.G[(size_t)pc*p.BN+pc]-2.f*p.G[(size_t)q*p.BN+pc],0.f);
        if(d2<best){best=d2;bc=cc;}
      }
      in=(bc==c);
    }
    unsigned long long mask=__ballot(in);
    int pre=__popcll(mask & ((lane==63)?0x7FFFFFFFFFFFFFFFull:((1ull<<lane)-1ull)));
    if(in) p.qidx[c*p.Q+base+pre]=q;
    base+=__popcll(mask);
  }
  if(lane==0) p.qcount[c]=base;
  int pc=p.Q+c;
  float gp=p.G[(size_t)pc*p.BN+pc];
  unsigned long long best=0xFFFFFFFFFFFFFFFFull;
  for(int t=lane;t<base;t+=64){
    int q=p.qidx[c*p.Q+t];
    float d2=fmaxf(p.G[(size_t)q*p.BN+q]+gp-2.f*p.G[(size_t)q*p.BN+pc],0.f);
    unsigned long long key=(((unsigned long long)f2key(d2))<<32)|(unsigned)t;
    if(key<best)best=key;
  }
  #pragma unroll
  for(int s=32;s>=1;s>>=1){
    unsigned long long o=shfl_xor_u64(best,s);
    if(o<best)best=o;
  }
  if(lane==0){
    int t=(int)(unsigned)(best&0xFFFFFFFFull);
    p.kq[c]=(base>0)? p.qidx[c*p.Q+t] : 0;
  }
}

__global__ void k_median(P p){
  __shared__ unsigned hist[256];
  __shared__ unsigned sPref; __shared__ int sTrem;
  __shared__ int sqidx[512];
  int c=blockIdx.x; int C=p.meta[0];
  int m=(c<C)? p.qcount[c]:0;
  int tid=threadIdx.x;
  if(m<2){ if(tid==0) p.thr[c]=INFINITY; return; }
  const int* qix;
  if(p.Q<=512){
    for(int t=tid;t<m;t+=blockDim.x) sqidx[t]=p.qidx[c*p.Q+t];
    __syncthreads();
    qix=sqidx;
  } else qix=p.qidx+c*p.Q;
  int total=m*m;
  unsigned* keys=p.cosk+(size_t)c*p.Q*p.Q;
  for(int t=tid;t<total;t+=blockDim.x){
    int a=t/m, b=t-a*m;
    keys[t]=f2key(p.cosq[(size_t)qix[a]*p.Q+qix[b]]);
  }
  if(tid==0){ sPref=0u; sTrem=(total-1)/2; }
  __syncthreads();
  unsigned prefmask=0u;
  for(int shift=24;shift>=0;shift-=8){
    hist[tid&255]=0u;
    __syncthreads();
    unsigned pref=sPref;
    for(int t=tid;t<total;t+=blockDim.x){
      unsigned key=keys[t];
      if((key&prefmask)==pref) atomicAdd(&hist[(key>>shift)&255],1u);
    }
    __syncthreads();
    if(tid==0){
      int trem=sTrem; unsigned cum=0;
      for(int b=0;b<256;b++){
        unsigned h=hist[b];
        if(cum+h>(unsigned)trem){ sPref=pref|((unsigned)b<<shift); sTrem=trem-(int)cum; break; }
        cum+=h;
      }
    }
    __syncthreads();
    prefmask|=(0xFFu<<shift);
  }
  if(tid==0) p.thr[c]=key2f(sPref);
}

__global__ void k_rowcnt(P p){
  int c=blockIdx.x; int C=p.meta[0];
  int m=(c<C)? p.qcount[c]:0;
  if(m<2){ if(threadIdx.x==0) p.paircnt[c]=0; return; }
  float th=p.thr[c];
  for(int a=threadIdx.x;a<m;a+=blockDim.x){
    int ia=p.qidx[c*p.Q+a]; int cnt=0;
    const float* row=p.cosq+(size_t)ia*p.Q;
    for(int b=a+1;b<m;b++){
      int ib=p.qidx[c*p.Q+b];
      cnt += (row[ib]>=th);
    }
    p.rowcnt[c*p.Q+a]=cnt;
  }
  __syncthreads();
  if(threadIdx.x==0){
    int run=0;
    for(int a=0;a<m;a++){p.rowoff[c*p.Q+a]=run; run+=p.rowcnt[c*p.Q+a];}
    p.paircnt[c]=run;
  }
}

__global__ void k_bases(P p){
  int C=p.meta[0]; int cur=p.Q;
  for(int c=0;c<C;c++){
    p.basev[c]=cur;
    if(p.qcount[c]>=2) cur += p.paircnt[c]+1;
  }
  int n=cur; if(n>p.NMAX)n=p.NMAX;
  p.meta[1]=n;
  int k=31-__clz(n); if(k<1)k=1; if(k>KMAX-1)k=KMAX-1;
  p.meta[2]=k;
  for(int t=0;t<64;t++) p.gmaxu[t]=0u;
}

__global__ void k_uv(P p){
  int r=blockIdx.x*blockDim.x+threadIdx.x;
  if(r>=p.NMAX)return;
  p.indeg[r]=0;
  if(r<p.Q){ p.uv[2*r]=r; p.uv[2*r+1]=r; }
}

__global__ void k_uvpairs(P p){
  int c=blockIdx.x; int C=p.meta[0];
  int m=(c<C)? p.qcount[c]:0;
  if(m<2)return;
  float th=p.thr[c];
  int bs=p.basev[c];
  for(int a=threadIdx.x;a<m;a+=blockDim.x){
    int ia=p.qidx[c*p.Q+a];
    int off=bs+p.rowoff[c*p.Q+a]; int cnt=0;
    const float* row=p.cosq+(size_t)ia*p.Q;
    for(int b=a+1;b<m;b++){
      int ib=p.qidx[c*p.Q+b];
      if(row[ib]>=th){
        int r=off+cnt;
        p.uv[2*r]=ia; p.uv[2*r+1]=ib;
        cnt++;
      }
    }
  }
  if(threadIdx.x==0){
    int r=bs+p.paircnt[c];
    p.uv[2*r]=p.Q+c; p.uv[2*r+1]=p.kq[c];
  }
}

// ---------- rn2 + packed candidate ----------
__global__ void k_rn2c(P p){
  int r=blockIdx.x*blockDim.x+threadIdx.x;
  int n=p.meta[1]; if(r>=n)return;
  int u=p.uv[2*r],v=p.uv[2*r+1];
  float hu=0.5f*(p.G[(size_t)u*p.BN+u]+p.G[(size_t)v*p.BN+u]);
  float hv=0.5f*(p.G[(size_t)u*p.BN+v]+p.G[(size_t)v*p.BN+v]);
  float rn=0.5f*(hu+hv);
  p.rn2[r]=rn;
  ((int4*)p.cand)[r]=make_int4(u,v,__float_as_int(rn),0);
}

// ---------- kNN scan: raw float-bit keys (d2>=0 -> monotone) ----------
template<int KSEL>
__device__ void knn_scan(const P& p,int n,int kp1,const float* sh,bool useSh,
                         const float* Gu,const float* Gv,float rni,
                         unsigned long long* wl){
  int lane=threadIdx.x&63; int w=threadIdx.x>>6;
  unsigned kf[KSEL]; int kj[KSEL];
  #pragma unroll
  for(int t=0;t<KSEL;t++){ kf[t]=0xFFFFFFFFu; kj[t]=0x7FFFFFFF; }
  unsigned thrw=0xFFFFFFFFu;
  int iters=(n+127)>>7;
  const int4* cand=(const int4*)p.cand;
  for(int it=0;it<iters;++it){
    int j=(it<<7)+(w<<6)+lane;
    unsigned key=0xFFFFFFFFu;
    if(j<n){
      int4 cd=cand[j];
      float dot = useSh ? (sh[cd.x]+sh[cd.y])
                        : 0.5f*(Gu[cd.x]+Gv[cd.x])+0.5f*(Gu[cd.y]+Gv[cd.y]);
      float d2=fmaxf(rni+__int_as_float(cd.z)-dot,0.f);
      key=__float_as_uint(d2);
    }
    if(key<=thrw && key<kf[KSEL-1]){
      int cj=j;
      #pragma unroll
      for(int t=0;t<KSEL;t++){
        bool lt = key<kf[t];
        unsigned nk = lt? key : kf[t];
        unsigned ok = lt? kf[t] : key;
        int nj = lt? cj : kj[t];
        int oj = lt? kj[t] : cj;
        kf[t]=nk; kj[t]=nj; key=ok; cj=oj;
      }
    }
    if((it&7)==7){
      unsigned v=kf[KSEL-1];
      #pragma unroll
      for(int s=32;s>=1;s>>=1){
        unsigned o=(unsigned)__shfl_xor((int)v,s,64);
        if(o<v)v=o;
      }
      thrw=v;
    }
  }
  for(int t=0;t<kp1;t++){
    unsigned long long mv=(((unsigned long long)kf[0])<<32)|(unsigned)kj[0];
    unsigned long long m=mv;
    #pragma unroll
    for(int s=32;s>=1;s>>=1){
      unsigned long long o=shfl_xor_u64(m,s);
      if(o<m)m=o;
    }
    if(mv==m){
      #pragma unroll
      for(int q=0;q<KSEL-1;q++){ kf[q]=kf[q+1]; kj[q]=kj[q+1]; }
      kf[KSEL-1]=0xFFFFFFFFu; kj[KSEL-1]=0x7FFFFFFF;
    }
    if(lane==0) wl[w*16+t]=m;
  }
}

__global__ void __launch_bounds__(128) k_knn(P p){
  __shared__ float sh[BNMAX];
  __shared__ unsigned long long wl[32];
  int i=blockIdx.x;
  int n=p.meta[1]; if(i>=n)return;
  int kp1=p.meta[2]+1;
  int u1=p.uv[2*i], v1=p.uv[2*i+1];
  const float* Gu=p.G+(size_t)u1*p.BN;
  const float* Gv=p.G+(size_t)v1*p.BN;
  bool useSh=(p.BN<=BNMAX);
  if(useSh){
    for(int d=threadIdx.x; d<p.BN; d+=128) sh[d]=0.5f*(Gu[d]+Gv[d]);
  }
  __syncthreads();
  float rni=p.rn2[i];
  if(kp1<=13) knn_scan<13>(p,n,kp1,sh,useSh,Gu,Gv,rni,wl);
  else        knn_scan<16>(p,n,kp1,sh,useSh,Gu,Gv,rni,wl);
  __syncthreads();
  if(threadIdx.x==0){
    int a=0,b=0;
    for(int t=0;t<kp1;t++){
      unsigned long long va=wl[a], vb=wl[16+b];
      unsigned long long m;
      if(va<=vb){m=va;a++;} else {m=vb;b++;}
      int j=(int)(unsigned)(m&0xFFFFFFFFull);
      float d2=__uint_as_float((unsigned)(m>>32));
      float dd=sqrtf(fmaxf(d2,1e-30f));
      if(t>=1){ p.nbrs[(size_t)i*KMAX+t-1]=j; p.dnb[(size_t)i*KMAX+t-1]=dd; }
      if(t==kp1-1) p.sigma[i]=dd+1e-8f;
    }
  }
}

// ---------- edge weights (+KMAX zero padding) + in-degree ----------
__global__ void k_wgtcnt(P p){
  int i=blockIdx.x*blockDim.x+threadIdx.x;
  int n=p.meta[1]; if(i>=n)return;
  int k=p.meta[2];
  float si=p.sigma[i];
  for(int q=0;q<k;q++){
    int j=p.nbrs[(size_t)i*KMAX+q];
    p.wgt[(size_t)i*KMAX+q]=expf(-p.dnb[(size_t)i*KMAX+q]/(si*p.sigma[j]));
    atomicAdd(&p.indeg[j],1);
  }
  for(int q=k;q<KMAX;q++){ p.nbrs[(size_t)i*KMAX+q]=i; p.wgt[(size_t)i*KMAX+q]=0.f; }
}

__global__ void k_scan(P p){
  __shared__ int part[TPB];
  int n=p.meta[1];
  int chunk=(n+TPB-1)/TPB;
  int beg=threadIdx.x*chunk, end=beg+chunk; if(end>n)end=n;
  int s=0;
  for(int i=beg;i<end;i++) s+=p.indeg[i];
  part[threadIdx.x]=s; __syncthreads();
  if(threadIdx.x==0){
    int run=0;
    for(int t=0;t<TPB;t++){int v=part[t];part[t]=run;run+=v;}
    p.inoff[n]=run;
  }
  __syncthreads();
  int run=part[threadIdx.x];
  for(int i=beg;i<end;i++){
    p.inoff[i]=run; p.cursor[i]=run; run+=p.indeg[i];
  }
}

__global__ void k_fill(P p){
  int i=blockIdx.x*blockDim.x+threadIdx.x;
  int n=p.meta[1]; if(i>=n)return;
  int k=p.meta[2];
  for(int q=0;q<k;q++){
    int dst=p.nbrs[(size_t)i*KMAX+q];
    int slot=atomicAdd(&p.cursor[dst],1);
    p.insrcU[slot]=i; p.inwU[slot]=p.wgt[(size_t)i*KMAX+q]; p.indst[slot]=dst;
  }
}

__global__ void k_rank(P p){
  int e=blockIdx.x*blockDim.x+threadIdx.x;
  int n=p.meta[1];
  int E=p.inoff[n];
  if(e>=E)return;
  int dst=p.indst[e];
  int b=p.inoff[dst], en=p.inoff[dst+1];
  int s=p.insrcU[e]; float w=p.inwU[e];
  int rank=0;
  for(int x=b;x<en;x++) rank += (p.insrcU[x]<s);
  p.inedge[b+rank]=make_int2(s,__float_as_int(w));
}

__global__ void k_dad(P p){
  int i=blockIdx.x*blockDim.x+threadIdx.x;
  int n=p.meta[1]; if(i>=n)return;
  int k=p.meta[2]; int C=p.meta[0];
  float s=0.f;
  for(int q=0;q<k;q++) s+=p.wgt[(size_t)i*KMAX+q];
  for(int e=p.inoff[i];e<p.inoff[i+1];e++) s+=__int_as_float(p.inedge[e].y);
  p.dinv[i]=1.f/(0.5f*s+1e-8f);
  int u=p.uv[2*i],v=p.uv[2*i+1];
  float rn=p.rn2[i]; float mn=INFINITY;
  #pragma unroll
  for(int c=0;c<CMAX;c++){
    float a=INFINITY;
    if(c<C){
      int pc=p.Q+c;
      a=rn+p.G[(size_t)pc*p.BN+pc]-(p.G[(size_t)u*p.BN+pc]+p.G[(size_t)v*p.BN+pc]);
      a=fmaxf(a,0.f);
      mn=fminf(mn,a);
    }
    p.amat[(size_t)i*CMAX+c]=a;
  }
  p.dmin[i]=sqrtf(fmaxf(mn,1e-30f));
}

__global__ void k_medd(P p){
  __shared__ unsigned hist[256];
  __shared__ unsigned sPref; __shared__ int sTrem;
  int n=p.meta[1];
  int tid=threadIdx.x;
  if(tid==0){ sPref=0u; sTrem=(n-1)/2; }
  __syncthreads();
  unsigned prefmask=0u;
  for(int shift=24;shift>=0;shift-=8){
    hist[tid&255]=0u;
    __syncthreads();
    unsigned pref=sPref;
    for(int i=tid;i<n;i+=blockDim.x){
      unsigned key=f2key(p.dmin[i]);
      if((key&prefmask)==pref) atomicAdd(&hist[(key>>shift)&255],1u);
    }
    __syncthreads();
    if(tid==0){
      int trem=sTrem; unsigned cum=0;
      for(int b=0;b<256;b++){
        unsigned h=hist[b];
        if(cum+h>(unsigned)trem){ sPref=pref|((unsigned)b<<shift); sTrem=trem-(int)cum; break; }
        cum+=h;
      }
    }
    __syncthreads();
    prefmask|=(0xFFu<<shift);
  }
  if(tid==0){
    float med=key2f(sPref);
    p.meddenom[0]=2.f*med*med+1e-8f;
  }
}

// ---------- lambda, scale, y0 -> ybufs[0] ----------
__global__ void k_y0(P p){
  int i=blockIdx.x*blockDim.x+threadIdx.x;
  int n=p.meta[1]; if(i>=n)return;
  float la=expf(-(p.dmin[i]*p.dmin[i])/p.meddenom[0]);
  p.scalev[i]=la*p.dinv[i];
  float mn=INFINITY;
  #pragma unroll
  for(int c=0;c<CMAX;c++) mn=fminf(mn,p.amat[(size_t)i*CMAX+c]);
  float ex[CMAX]; float sum=0.f;
  #pragma unroll
  for(int c=0;c<CMAX;c++){
    float e=expf(mn-p.amat[(size_t)i*CMAX+c]);   // INF -> 0
    ex[c]=e; sum+=e;
  }
  float inv=1.f/sum;
  #pragma unroll
  for(int c=0;c<CMAX;c++) p.ybufs[(size_t)i*CMAX+c]=ex[c]*inv;
}

// ---------- one propagation step: snapshot buffers, no state machine ----------
__global__ void __launch_bounds__(64) k_step(P p,int t){
  int n=p.meta[1];
  size_t st=(size_t)p.NMAX*CMAX;
  const float* cur=p.ybufs+(size_t)t*st;
  float*       nxt=p.ybufs+(size_t)(t+1)*st;
  int i=blockIdx.x*blockDim.x+threadIdx.x;
  float dmx=0.f;
  if(i<n){
    float wax=0,way=0,waz=0,waw=0,wbx=0,wby=0,wbz=0,wbw=0;
    #pragma unroll
    for(int q=0;q<KMAX;q++){              // zero-padded to KMAX
      int j=p.nbrs[(size_t)i*KMAX+q];
      float w=p.wgt[(size_t)i*KMAX+q];
      const float4* yr=(const float4*)(cur+(size_t)j*CMAX);
      float4 y0=yr[0],y1=yr[1];
      wax+=w*y0.x; way+=w*y0.y; waz+=w*y0.z; waw+=w*y0.w;
      wbx+=w*y1.x; wby+=w*y1.y; wbz+=w*y1.z; wbw+=w*y1.w;
    }
    int e1=p.inoff[i+1];
    for(int e=p.inoff[i];e<e1;e++){
      int2 e2=p.inedge[e];
      int j=e2.x; float w=__int_as_float(e2.y);
      const float4* yr=(const float4*)(cur+(size_t)j*CMAX);
      float4 y0=yr[0],y1=yr[1];
      wax+=w*y0.x; way+=w*y0.y; waz+=w*y0.z; waw+=w*y0.w;
      wbx+=w*y1.x; wby+=w*y1.y; wbz+=w*y1.z; wbw+=w*y1.w;
    }
    float sc=p.scalev[i]*0.5f;
    const float4* am=(const float4*)(p.amat+(size_t)i*CMAX);
    float4 a0=am[0],a1=am[1];
    float l0=sc*wax-a0.x, l1=sc*way-a0.y, l2=sc*waz-a0.z, l3=sc*waw-a0.w;
    float l4=sc*wbx-a1.x, l5=sc*wby-a1.y, l6=sc*wbz-a1.z, l7=sc*wbw-a1.w;
    float mx=fmaxf(fmaxf(fmaxf(l0,l1),fmaxf(l2,l3)),fmaxf(fmaxf(l4,l5),fmaxf(l6,l7)));
    float x0=expf(l0-mx),x1=expf(l1-mx),x2=expf(l2-mx),x3=expf(l3-mx);
    float x4=expf(l4-mx),x5=expf(l5-mx),x6=expf(l6-mx),x7=expf(l7-mx);
    float inv=1.f/(x0+x1+x2+x3+x4+x5+x6+x7);
    float4 o0=make_float4(x0*inv,x1*inv,x2*inv,x3*inv);
    float4 o1=make_float4(x4*inv,x5*inv,x6*inv,x7*inv);
    const float4* cr=(const float4*)(cur+(size_t)i*CMAX);
    float4 c0=cr[0],c1=cr[1];
    dmx=fmaxf(dmx,fabsf(o0.x-c0.x)); dmx=fmaxf(dmx,fabsf(o0.y-c0.y));
    dmx=fmaxf(dmx,fabsf(o0.z-c0.z)); dmx=fmaxf(dmx,fabsf(o0.w-c0.w));
    dmx=fmaxf(dmx,fabsf(o1.x-c1.x)); dmx=fmaxf(dmx,fabsf(o1.y-c1.y));
    dmx=fmaxf(dmx,fabsf(o1.z-c1.z)); dmx=fmaxf(dmx,fabsf(o1.w-c1.w));
    float4* nr=(float4*)(nxt+(size_t)i*CMAX);
    nr[0]=o0; nr[1]=o1;
  }
  #pragma unroll
  for(int s=32;s>=1;s>>=1) dmx=fmaxf(dmx,__shfl_xor(dmx,s,64));
  if(threadIdx.x==0)
    atomicMax(p.gmaxu+t,__float_as_uint(dmx));   // dmx>=0 -> bits monotone
}

// ---------- final: first-crossing selection + argmax ----------
__global__ void k_arg(P p){
  __shared__ int sT;
  if(threadIdx.x==0){
    int tsel=NSTEP;
    for(int t=0;t<NSTEP;t++){
      if(__uint_as_float(p.gmaxu[t])<1e-4f){ tsel=t; break; }
    }
    sT=tsel;
  }
  __syncthreads();
  int q=blockIdx.x*blockDim.x+threadIdx.x;
  if(q>=p.Q)return;
  int C=p.meta[0];
  const float* cur=p.ybufs+(size_t)sT*(size_t)p.NMAX*CMAX;
  float best=cur[(size_t)q*CMAX+0]; int bc=0;
  for(int c=1;c<C;c++){
    float v=cur[(size_t)q*CMAX+c];
    if(v>best){best=v;bc=c;}
  }
  p.outp[q]=bc;
}

// =======================================================================

static void make_layout(char* base,int S,int Q,int D,int BN,long N,
                        const float*fs,const int*ys,const float*fq,
                        int* outp, P* pp, size_t* need){
  size_t off=0;
  auto A=[&](size_t b)->char*{
    size_t o=(off+255)&~(size_t)255; off=o+b; return base+o;
  };
  P p{};
  p.fs=fs;p.ys=ys;p.fq=fq;p.S=S;p.Q=Q;p.D=D;p.BN=BN;p.NMAX=(int)N;
  p.proto=(float*)A(4ul*CMAX*D);
  p.G=(float*)A(4ul*(size_t)BN*BN);
  p.cosq=(float*)A(4ul*(size_t)Q*Q);
  p.cls=(int*)A(4ul*CMAX);
  p.scount=(int*)A(4ul*CMAX);
  p.qcount=(int*)A(4ul*CMAX);
  p.qidx=(int*)A(4ul*CMAX*Q);
  p.kq=(int*)A(4ul*CMAX);
  p.thr=(float*)A(4ul*CMAX);
  p.rowcnt=(int*)A(4ul*CMAX*Q);
  p.rowoff=(int*)A(4ul*CMAX*Q);
  p.paircnt=(int*)A(4ul*CMAX);
  p.basev=(int*)A(4ul*CMAX);
  p.meta=(int*)A(4ul*16);
  p.uv=(int*)A(8ul*N);
  p.rn2=(float*)A(4ul*N);
  p.cand=(int*)A(16ul*N);
  p.nbrs=(int*)A(4ul*KMAX*N);
  p.dnb=(float*)A(4ul*KMAX*N);
  p.wgt=(float*)A(4ul*KMAX*N);
  p.sigma=(float*)A(4ul*N);
  p.indeg=(int*)A(4ul*N);
  p.inoff=(int*)A(4ul*(N+1));
  p.cursor=(int*)A(4ul*N);
  p.insrcU=(int*)A(4ul*KMAX*N);
  p.inwU=(float*)A(4ul*KMAX*N);
  p.indst=(int*)A(4ul*KMAX*N);
  p.inedge=(int2*)A(8ul*KMAX*N);
  p.cosk=(unsigned*)A(4ul*CMAX*(size_t)Q*Q);
  p.gmaxu=(unsigned*)A(4ul*64);
  p.amat=(float*)A(4ul*CMAX*N);
  p.dinv=(float*)A(4ul*N);
  p.dmin=(float*)A(4ul*N);
  p.scalev=(float*)A(4ul*N);
  p.ybufs=(float*)A(4ul*CMAX*(size_t)N*(NSTEP+1));
  p.meddenom=(float*)A(4ul*4);
  p.outp=outp;
  *pp=p; *need=off;
}

extern "C" void kernel_launch(void* const* d_in, const int* in_sizes, int n_in,
                              void* d_out, int out_size, void* d_ws, size_t ws_size,
                              hipStream_t stream){
  const float* fs=(const float*)d_in[0];
  const int*   ys=(const int*)d_in[1];
  const float* fq=(const float*)d_in[2];
  int S=in_sizes[1];
  int D=in_sizes[0]/S;
  int Q=in_sizes[2]/D;
  int BN=Q+CMAX;

  long full=(long)Q + (long)Q*(Q-1)/2 + CMAX;
  long cand[4]={full,16384,8192,5000};
  P p{}; size_t need=0; int NMAX=(int)cand[3];
  for(int ci=0;ci<4;ci++){
    long N=cand[ci]; if(N<Q+CMAX)N=Q+CMAX;
    make_layout((char*)d_ws,S,Q,D,BN,N,fs,ys,fq,(int*)d_out,&p,&need);
    NMAX=(int)N;
    if(need<=ws_size) break;
  }

  int gN=(NMAX+TPB-1)/TPB;
  long gEl=((long)NMAX*KMAX+TPB-1)/TPB;
  int gE=(int)gEl;
  int gS=(NMAX+63)/64;

  k_init   <<<1, 64, 0, stream>>>(p);
  k_proto  <<<CMAX, TPB, 0, stream>>>(p);
  k_gram   <<<BN, TPB, 0, stream>>>(p);
  k_cos    <<<(Q*Q+TPB-1)/TPB, TPB, 0, stream>>>(p);
  k_qidx   <<<CMAX, 64, 0, stream>>>(p);
  k_median <<<CMAX, TPB, 0, stream>>>(p);
  k_rowcnt <<<CMAX, TPB, 0, stream>>>(p);
  k_bases  <<<1, 1, 0, stream>>>(p);
  k_uv     <<<gN, TPB, 0, stream>>>(p);
  k_uvpairs<<<CMAX, TPB, 0, stream>>>(p);
  k_rn2c   <<<gN, TPB, 0, stream>>>(p);
  k_knn    <<<NMAX, 128, 0, stream>>>(p);
  k_wgtcnt <<<gN, TPB, 0, stream>>>(p);
  k_scan   <<<1, TPB, 0, stream>>>(p);
  k_fill   <<<gN, TPB, 0, stream>>>(p);
  k_rank   <<<gE, TPB, 0, stream>>>(p);
  k_dad    <<<gN, TPB, 0, stream>>>(p);
  k_medd   <<<1, TPB, 0, stream>>>(p);
  k_y0     <<<gN, TPB, 0, stream>>>(p);
  for(int t=0;t<NSTEP;t++)
    k_step <<<gS, 64, 0, stream>>>(p, t);
  k_arg    <<<(Q+TPB-1)/TPB, TPB, 0, stream>>>(p);
}

// Round 10
// 563.337 us; speedup vs baseline: 2.4110x; 2.4110x over previous
//
#include <hip/hip_runtime.h>
#include <math.h>

#define CMAX 8
#define KMAX 16
#define TPB 256
#define BNMAX 1024

struct P {
  const float* fs; const int* ys; const float* fq;
  int S, Q, D, BN, NMAX;
  float* proto;
  float* G;
  float* cosq;
  int* cls; int* scount; int* qcount; int* qidx; int* kq;
  float* thr;
  int* rowcnt; int* rowoff; int* paircnt; int* basev;
  int* meta;     // [0]=C [1]=n [2]=k [3]=done [4]=parity [5]=blkctr
  int* uv;
  float* rn2;
  int* cand;     // int4 per row: u,v,bits(rn2),0
  int* nbrs; float* dnb; float* wgt; float* sigma;
  int* indeg; int* inoff; int* cursor;
  int* insrcU; float* inwU; int* indst;
  int2* inedge;  // packed rank-sorted transpose edges (src, w-bits)
  unsigned* cosk;
  unsigned* gmaxu;
  float* amat; float* dinv; float* dmin; float* scalev;
  float* yA; float* yB;
  float* meddenom;
  int* outp;
};

__device__ inline unsigned f2key(float f){
  unsigned b=__float_as_uint(f);
  return (b&0x80000000u)? ~b : (b|0x80000000u);
}
__device__ inline float key2f(unsigned k){
  unsigned b=(k&0x80000000u)? (k^0x80000000u) : ~k;
  return __uint_as_float(b);
}
__device__ inline unsigned long long shfl_xor_u64(unsigned long long v,int m){
  unsigned lo=(unsigned)v, hi=(unsigned)(v>>32);
  lo=__shfl_xor(lo,m,64); hi=__shfl_xor(hi,m,64);
  return (((unsigned long long)hi)<<32)|lo;
}

// ---------- setup ----------
__global__ void k_init(P p){
  if (threadIdx.x==0){
    int labs[CMAX]; int cnt[CMAX]; int C=0;
    for (int s=0;s<p.S;s++){
      int l=p.ys[s]; int f=-1;
      for(int c=0;c<C;c++) if(labs[c]==l){f=c;break;}
      if(f<0){ if(C<CMAX){labs[C]=l;cnt[C]=1;C++;} }
      else cnt[f]++;
    }
    for(int a=0;a<C;a++)for(int b=a+1;b<C;b++)
      if(labs[b]<labs[a]){int t=labs[a];labs[a]=labs[b];labs[b]=t;
                          t=cnt[a];cnt[a]=cnt[b];cnt[b]=t;}
    for(int c=0;c<C;c++){p.cls[c]=labs[c];p.scount[c]=cnt[c];}
    p.meta[0]=C;
  }
}

__global__ void k_proto(P p){
  int c=blockIdx.x; int C=p.meta[0];
  for(int d=threadIdx.x; d<p.D; d+=blockDim.x){
    float s=0.f;
    if(c<C){
      int lab=p.cls[c];
      for(int j=0;j<p.S;j++) if(p.ys[j]==lab) s+=p.fs[(size_t)j*p.D+d];
      s/= (float)p.scount[c];
    }
    p.proto[(size_t)c*p.D+d]=s;
  }
}

__global__ void k_gram(P p){
  __shared__ float arow[1024];
  int a=blockIdx.x;
  const float* ra = (a<p.Q)? p.fq + (size_t)a*p.D : p.proto + (size_t)(a-p.Q)*p.D;
  const float* A = ra;
  if(p.D<=1024){
    for(int d=threadIdx.x; d<p.D; d+=blockDim.x) arow[d]=ra[d];
    __syncthreads();
    A=(const float*)arow;
  }
  int D4=p.D>>2; int Dt=D4<<2;
  for(int b=threadIdx.x; b<p.BN; b+=blockDim.x){
    const float* rb=(b<p.Q)? p.fq+(size_t)b*p.D : p.proto+(size_t)(b-p.Q)*p.D;
    const float4* a4=(const float4*)A;
    const float4* b4=(const float4*)rb;
    float s=0.f;
    #pragma unroll 4
    for(int d=0;d<D4;d++){
      float4 x=a4[d], y=b4[d];
      s += x.x*y.x + x.y*y.y + x.z*y.z + x.w*y.w;
    }
    for(int d=Dt;d<p.D;d++) s += A[d]*rb[d];
    p.G[(size_t)a*p.BN+b]=s;
  }
}

__global__ void k_cos(P p){
  int t=blockIdx.x*blockDim.x+threadIdx.x;
  if(t>=p.Q*p.Q)return;
  int i=t/p.Q, j=t%p.Q;
  p.cosq[t]=p.G[(size_t)i*p.BN+j]/(sqrtf(p.G[(size_t)i*p.BN+i])*sqrtf(p.G[(size_t)j*p.BN+j]));
}

// ---------- per-class index lists + kq (ybt computed inline) ----------
__global__ void k_qidx(P p){
  int c=blockIdx.x; int C=p.meta[0];
  int lane=threadIdx.x;
  if(c>=C){ if(lane==0){p.qcount[c]=0;p.kq[c]=0;} return; }
  int base=0;
  for(int q0=0;q0<p.Q;q0+=64){
    int q=q0+lane;
    bool in=false;
    if(q<p.Q){
      float gq=p.G[(size_t)q*p.BN+q];
      float best=INFINITY; int bc=0;
      for(int cc=0;cc<C;cc++){
        int pc=p.Q+cc;
        float d2=fmaxf(gq+p.G[(size_t)pc*p.BN+pc]-2.f*p.G[(size_t)q*p.BN+pc],0.f);
        if(d2<best){best=d2;bc=cc;}
      }
      in=(bc==c);
    }
    unsigned long long mask=__ballot(in);
    int pre=__popcll(mask & ((lane==63)?0x7FFFFFFFFFFFFFFFull:((1ull<<lane)-1ull)));
    if(in) p.qidx[c*p.Q+base+pre]=q;
    base+=__popcll(mask);
  }
  if(lane==0) p.qcount[c]=base;
  int pc=p.Q+c;
  float gp=p.G[(size_t)pc*p.BN+pc];
  unsigned long long best=0xFFFFFFFFFFFFFFFFull;
  for(int t=lane;t<base;t+=64){
    int q=p.qidx[c*p.Q+t];
    float d2=fmaxf(p.G[(size_t)q*p.BN+q]+gp-2.f*p.G[(size_t)q*p.BN+pc],0.f);
    unsigned long long key=(((unsigned long long)f2key(d2))<<32)|(unsigned)t;
    if(key<best)best=key;
  }
  #pragma unroll
  for(int s=32;s>=1;s>>=1){
    unsigned long long o=shfl_xor_u64(best,s);
    if(o<best)best=o;
  }
  if(lane==0){
    int t=(int)(unsigned)(best&0xFFFFFFFFull);
    p.kq[c]=(base>0)? p.qidx[c*p.Q+t] : 0;
  }
}

__global__ void k_median(P p){
  __shared__ unsigned hist[256];
  __shared__ unsigned sPref; __shared__ int sTrem;
  __shared__ int sqidx[512];
  int c=blockIdx.x; int C=p.meta[0];
  int m=(c<C)? p.qcount[c]:0;
  int tid=threadIdx.x;
  if(m<2){ if(tid==0) p.thr[c]=INFINITY; return; }
  const int* qix;
  if(p.Q<=512){
    for(int t=tid;t<m;t+=blockDim.x) sqidx[t]=p.qidx[c*p.Q+t];
    __syncthreads();
    qix=sqidx;
  } else qix=p.qidx+c*p.Q;
  int total=m*m;
  unsigned* keys=p.cosk+(size_t)c*p.Q*p.Q;
  for(int t=tid;t<total;t+=blockDim.x){
    int a=t/m, b=t-a*m;
    keys[t]=f2key(p.cosq[(size_t)qix[a]*p.Q+qix[b]]);
  }
  if(tid==0){ sPref=0u; sTrem=(total-1)/2; }
  __syncthreads();
  unsigned prefmask=0u;
  for(int shift=24;shift>=0;shift-=8){
    hist[tid&255]=0u;
    __syncthreads();
    unsigned pref=sPref;
    for(int t=tid;t<total;t+=blockDim.x){
      unsigned key=keys[t];
      if((key&prefmask)==pref) atomicAdd(&hist[(key>>shift)&255],1u);
    }
    __syncthreads();
    if(tid==0){
      int trem=sTrem; unsigned cum=0;
      for(int b=0;b<256;b++){
        unsigned h=hist[b];
        if(cum+h>(unsigned)trem){ sPref=pref|((unsigned)b<<shift); sTrem=trem-(int)cum; break; }
        cum+=h;
      }
    }
    __syncthreads();
    prefmask|=(0xFFu<<shift);
  }
  if(tid==0) p.thr[c]=key2f(sPref);
}

__global__ void k_rowcnt(P p){
  int c=blockIdx.x; int C=p.meta[0];
  int m=(c<C)? p.qcount[c]:0;
  if(m<2){ if(threadIdx.x==0) p.paircnt[c]=0; return; }
  float th=p.thr[c];
  for(int a=threadIdx.x;a<m;a+=blockDim.x){
    int ia=p.qidx[c*p.Q+a]; int cnt=0;
    const float* row=p.cosq+(size_t)ia*p.Q;
    for(int b=a+1;b<m;b++){
      int ib=p.qidx[c*p.Q+b];
      cnt += (row[ib]>=th);
    }
    p.rowcnt[c*p.Q+a]=cnt;
  }
  __syncthreads();
  if(threadIdx.x==0){
    int run=0;
    for(int a=0;a<m;a++){p.rowoff[c*p.Q+a]=run; run+=p.rowcnt[c*p.Q+a];}
    p.paircnt[c]=run;
  }
}

__global__ void k_bases(P p){
  int C=p.meta[0]; int cur=p.Q;
  for(int c=0;c<C;c++){
    p.basev[c]=cur;
    if(p.qcount[c]>=2) cur += p.paircnt[c]+1;
  }
  int n=cur; if(n>p.NMAX)n=p.NMAX;
  p.meta[1]=n;
  int k=31-__clz(n); if(k<1)k=1; if(k>KMAX-1)k=KMAX-1;
  p.meta[2]=k;
  p.meta[3]=0;   // done
  p.meta[4]=0;   // parity
  p.meta[5]=0;   // block counter
  for(int t=0;t<64;t++) p.gmaxu[t]=0u;
}

__global__ void k_uv(P p){
  int r=blockIdx.x*blockDim.x+threadIdx.x;
  if(r>=p.NMAX)return;
  p.indeg[r]=0;
  if(r<p.Q){ p.uv[2*r]=r; p.uv[2*r+1]=r; }
}

__global__ void k_uvpairs(P p){
  int c=blockIdx.x; int C=p.meta[0];
  int m=(c<C)? p.qcount[c]:0;
  if(m<2)return;
  float th=p.thr[c];
  int bs=p.basev[c];
  for(int a=threadIdx.x;a<m;a+=blockDim.x){
    int ia=p.qidx[c*p.Q+a];
    int off=bs+p.rowoff[c*p.Q+a]; int cnt=0;
    const float* row=p.cosq+(size_t)ia*p.Q;
    for(int b=a+1;b<m;b++){
      int ib=p.qidx[c*p.Q+b];
      if(row[ib]>=th){
        int r=off+cnt;
        p.uv[2*r]=ia; p.uv[2*r+1]=ib;
        cnt++;
      }
    }
  }
  if(threadIdx.x==0){
    int r=bs+p.paircnt[c];
    p.uv[2*r]=p.Q+c; p.uv[2*r+1]=p.kq[c];
  }
}

// ---------- rn2 + packed candidate ----------
__global__ void k_rn2c(P p){
  int r=blockIdx.x*blockDim.x+threadIdx.x;
  int n=p.meta[1]; if(r>=n)return;
  int u=p.uv[2*r],v=p.uv[2*r+1];
  float hu=0.5f*(p.G[(size_t)u*p.BN+u]+p.G[(size_t)v*p.BN+u]);
  float hv=0.5f*(p.G[(size_t)u*p.BN+v]+p.G[(size_t)v*p.BN+v]);
  float rn=0.5f*(hu+hv);
  p.rn2[r]=rn;
  ((int4*)p.cand)[r]=make_int4(u,v,__float_as_int(rn),0);
}

// ---------- kNN scan: 2 waves per row, 32-bit key chains ----------
template<int KSEL>
__device__ void knn_scan(const P& p,int n,int kp1,const float* sh,bool useSh,
                         const float* Gu,const float* Gv,float rni,
                         unsigned long long* wl){
  int lane=threadIdx.x&63; int w=threadIdx.x>>6;
  unsigned kf[KSEL]; int kj[KSEL];
  #pragma unroll
  for(int t=0;t<KSEL;t++){ kf[t]=0xFFFFFFFFu; kj[t]=0x7FFFFFFF; }
  unsigned thrw=0xFFFFFFFFu;
  int iters=(n+127)>>7;
  const int4* cand=(const int4*)p.cand;
  for(int it=0;it<iters;++it){
    int j=(it<<7)+(w<<6)+lane;
    unsigned key=0xFFFFFFFFu;
    if(j<n){
      int4 cd=cand[j];
      float dot = useSh ? (sh[cd.x]+sh[cd.y])
                        : 0.5f*(Gu[cd.x]+Gv[cd.x])+0.5f*(Gu[cd.y]+Gv[cd.y]);
      float d2=fmaxf(rni+__int_as_float(cd.z)-dot,0.f);
      key=__float_as_uint(d2);
    }
    if(key<=thrw && key<kf[KSEL-1]){
      int cj=j;
      #pragma unroll
      for(int t=0;t<KSEL;t++){
        bool lt = key<kf[t];
        unsigned nk = lt? key : kf[t];
        unsigned ok = lt? kf[t] : key;
        int nj = lt? cj : kj[t];
        int oj = lt? kj[t] : cj;
        kf[t]=nk; kj[t]=nj; key=ok; cj=oj;
      }
    }
    if((it&7)==7){
      unsigned v=kf[KSEL-1];
      #pragma unroll
      for(int s=32;s>=1;s>>=1){
        unsigned o=(unsigned)__shfl_xor((int)v,s,64);
        if(o<v)v=o;
      }
      thrw=v;
    }
  }
  for(int t=0;t<kp1;t++){
    unsigned long long mv=(((unsigned long long)kf[0])<<32)|(unsigned)kj[0];
    unsigned long long m=mv;
    #pragma unroll
    for(int s=32;s>=1;s>>=1){
      unsigned long long o=shfl_xor_u64(m,s);
      if(o<m)m=o;
    }
    if(mv==m){
      #pragma unroll
      for(int q=0;q<KSEL-1;q++){ kf[q]=kf[q+1]; kj[q]=kj[q+1]; }
      kf[KSEL-1]=0xFFFFFFFFu; kj[KSEL-1]=0x7FFFFFFF;
    }
    if(lane==0) wl[w*16+t]=m;
  }
}

__global__ void __launch_bounds__(128) k_knn(P p){
  __shared__ float sh[BNMAX];
  __shared__ unsigned long long wl[32];
  int i=blockIdx.x;
  int n=p.meta[1]; if(i>=n)return;
  int kp1=p.meta[2]+1;
  int u1=p.uv[2*i], v1=p.uv[2*i+1];
  const float* Gu=p.G+(size_t)u1*p.BN;
  const float* Gv=p.G+(size_t)v1*p.BN;
  bool useSh=(p.BN<=BNMAX);
  if(useSh){
    for(int d=threadIdx.x; d<p.BN; d+=128) sh[d]=0.5f*(Gu[d]+Gv[d]);
  }
  __syncthreads();
  float rni=p.rn2[i];
  if(kp1<=13) knn_scan<13>(p,n,kp1,sh,useSh,Gu,Gv,rni,wl);
  else        knn_scan<16>(p,n,kp1,sh,useSh,Gu,Gv,rni,wl);
  __syncthreads();
  if(threadIdx.x==0){
    int a=0,b=0;
    for(int t=0;t<kp1;t++){
      unsigned long long va=wl[a], vb=wl[16+b];
      unsigned long long m;
      if(va<=vb){m=va;a++;} else {m=vb;b++;}
      int j=(int)(unsigned)(m&0xFFFFFFFFull);
      float d2=__uint_as_float((unsigned)(m>>32));
      float dd=sqrtf(fmaxf(d2,1e-30f));
      if(t>=1){ p.nbrs[(size_t)i*KMAX+t-1]=j; p.dnb[(size_t)i*KMAX+t-1]=dd; }
      if(t==kp1-1) p.sigma[i]=dd+1e-8f;
    }
  }
}

// ---------- edge weights (+KMAX zero padding) + in-degree ----------
__global__ void k_wgtcnt(P p){
  int i=blockIdx.x*blockDim.x+threadIdx.x;
  int n=p.meta[1]; if(i>=n)return;
  int k=p.meta[2];
  float si=p.sigma[i];
  for(int q=0;q<k;q++){
    int j=p.nbrs[(size_t)i*KMAX+q];
    p.wgt[(size_t)i*KMAX+q]=expf(-p.dnb[(size_t)i*KMAX+q]/(si*p.sigma[j]));
    atomicAdd(&p.indeg[j],1);
  }
  for(int q=k;q<KMAX;q++){ p.nbrs[(size_t)i*KMAX+q]=i; p.wgt[(size_t)i*KMAX+q]=0.f; }
}

__global__ void k_scan(P p){
  __shared__ int part[TPB];
  int n=p.meta[1];
  int chunk=(n+TPB-1)/TPB;
  int beg=threadIdx.x*chunk, end=beg+chunk; if(end>n)end=n;
  int s=0;
  for(int i=beg;i<end;i++) s+=p.indeg[i];
  part[threadIdx.x]=s; __syncthreads();
  if(threadIdx.x==0){
    int run=0;
    for(int t=0;t<TPB;t++){int v=part[t];part[t]=run;run+=v;}
    p.inoff[n]=run;
  }
  __syncthreads();
  int run=part[threadIdx.x];
  for(int i=beg;i<end;i++){
    p.inoff[i]=run; p.cursor[i]=run; run+=p.indeg[i];
  }
}

__global__ void k_fill(P p){
  int i=blockIdx.x*blockDim.x+threadIdx.x;
  int n=p.meta[1]; if(i>=n)return;
  int k=p.meta[2];
  for(int q=0;q<k;q++){
    int dst=p.nbrs[(size_t)i*KMAX+q];
    int slot=atomicAdd(&p.cursor[dst],1);
    p.insrcU[slot]=i; p.inwU[slot]=p.wgt[(size_t)i*KMAX+q]; p.indst[slot]=dst;
  }
}

__global__ void k_rank(P p){
  int e=blockIdx.x*blockDim.x+threadIdx.x;
  int n=p.meta[1];
  int E=p.inoff[n];
  if(e>=E)return;
  int dst=p.indst[e];
  int b=p.inoff[dst], en=p.inoff[dst+1];
  int s=p.insrcU[e]; float w=p.inwU[e];
  int rank=0;
  for(int x=b;x<en;x++) rank += (p.insrcU[x]<s);
  p.inedge[b+rank]=make_int2(s,__float_as_int(w));
}

__global__ void k_dad(P p){
  int i=blockIdx.x*blockDim.x+threadIdx.x;
  int n=p.meta[1]; if(i>=n)return;
  int k=p.meta[2]; int C=p.meta[0];
  float s=0.f;
  for(int q=0;q<k;q++) s+=p.wgt[(size_t)i*KMAX+q];
  for(int e=p.inoff[i];e<p.inoff[i+1];e++) s+=__int_as_float(p.inedge[e].y);
  p.dinv[i]=1.f/(0.5f*s+1e-8f);
  int u=p.uv[2*i],v=p.uv[2*i+1];
  float rn=p.rn2[i]; float mn=INFINITY;
  #pragma unroll
  for(int c=0;c<CMAX;c++){
    float a=INFINITY;
    if(c<C){
      int pc=p.Q+c;
      a=rn+p.G[(size_t)pc*p.BN+pc]-(p.G[(size_t)u*p.BN+pc]+p.G[(size_t)v*p.BN+pc]);
      a=fmaxf(a,0.f);
      mn=fminf(mn,a);
    }
    p.amat[(size_t)i*CMAX+c]=a;
  }
  p.dmin[i]=sqrtf(fmaxf(mn,1e-30f));
}

__global__ void k_medd(P p){
  __shared__ unsigned hist[256];
  __shared__ unsigned sPref; __shared__ int sTrem;
  int n=p.meta[1];
  int tid=threadIdx.x;
  if(tid==0){ sPref=0u; sTrem=(n-1)/2; }
  __syncthreads();
  unsigned prefmask=0u;
  for(int shift=24;shift>=0;shift-=8){
    hist[tid&255]=0u;
    __syncthreads();
    unsigned pref=sPref;
    for(int i=tid;i<n;i+=blockDim.x){
      unsigned key=f2key(p.dmin[i]);
      if((key&prefmask)==pref) atomicAdd(&hist[(key>>shift)&255],1u);
    }
    __syncthreads();
    if(tid==0){
      int trem=sTrem; unsigned cum=0;
      for(int b=0;b<256;b++){
        unsigned h=hist[b];
        if(cum+h>(unsigned)trem){ sPref=pref|((unsigned)b<<shift); sTrem=trem-(int)cum; break; }
        cum+=h;
      }
    }
    __syncthreads();
    prefmask|=(0xFFu<<shift);
  }
  if(tid==0){
    float med=key2f(sPref);
    p.meddenom[0]=2.f*med*med+1e-8f;
  }
}

// ---------- lambda, scale, y0 -> yA ----------
__global__ void k_y0(P p){
  int i=blockIdx.x*blockDim.x+threadIdx.x;
  int n=p.meta[1]; if(i>=n)return;
  float la=expf(-(p.dmin[i]*p.dmin[i])/p.meddenom[0]);
  p.scalev[i]=la*p.dinv[i];
  float mn=INFINITY;
  #pragma unroll
  for(int c=0;c<CMAX;c++) mn=fminf(mn,p.amat[(size_t)i*CMAX+c]);
  float ex[CMAX]; float sum=0.f;
  #pragma unroll
  for(int c=0;c<CMAX;c++){
    float e=expf(mn-p.amat[(size_t)i*CMAX+c]);   // INF -> 0
    ex[c]=e; sum+=e;
  }
  float inv=1.f/sum;
  #pragma unroll
  for(int c=0;c<CMAX;c++) p.yA[(size_t)i*CMAX+c]=ex[c]*inv;
}

// ---------- one propagation step: yA/yB parity + freeze state (proven R7 shape) ----------
__global__ void __launch_bounds__(64) k_step(P p,int t){
  if(p.meta[3]) return;                 // converged earlier: y frozen, near-free
  int n=p.meta[1];
  int par=p.meta[4];
  float* cur=par? p.yB : p.yA;
  float* nxt=par? p.yA : p.yB;
  int i=blockIdx.x*blockDim.x+threadIdx.x;
  float dmx=0.f;
  if(i<n){
    float wax=0,way=0,waz=0,waw=0,wbx=0,wby=0,wbz=0,wbw=0;
    #pragma unroll
    for(int q=0;q<KMAX;q++){              // zero-padded to KMAX
      int j=p.nbrs[(size_t)i*KMAX+q];
      float w=p.wgt[(size_t)i*KMAX+q];
      const float4* yr=(const float4*)(cur+(size_t)j*CMAX);
      float4 y0=yr[0],y1=yr[1];
      wax+=w*y0.x; way+=w*y0.y; waz+=w*y0.z; waw+=w*y0.w;
      wbx+=w*y1.x; wby+=w*y1.y; wbz+=w*y1.z; wbw+=w*y1.w;
    }
    int e1=p.inoff[i+1];
    for(int e=p.inoff[i];e<e1;e++){
      int2 e2=p.inedge[e];
      int j=e2.x; float w=__int_as_float(e2.y);
      const float4* yr=(const float4*)(cur+(size_t)j*CMAX);
      float4 y0=yr[0],y1=yr[1];
      wax+=w*y0.x; way+=w*y0.y; waz+=w*y0.z; waw+=w*y0.w;
      wbx+=w*y1.x; wby+=w*y1.y; wbz+=w*y1.z; wbw+=w*y1.w;
    }
    float sc=p.scalev[i]*0.5f;
    const float4* am=(const float4*)(p.amat+(size_t)i*CMAX);
    float4 a0=am[0],a1=am[1];
    float l0=sc*wax-a0.x, l1=sc*way-a0.y, l2=sc*waz-a0.z, l3=sc*waw-a0.w;
    float l4=sc*wbx-a1.x, l5=sc*wby-a1.y, l6=sc*wbz-a1.z, l7=sc*wbw-a1.w;
    float mx=fmaxf(fmaxf(fmaxf(l0,l1),fmaxf(l2,l3)),fmaxf(fmaxf(l4,l5),fmaxf(l6,l7)));
    float x0=expf(l0-mx),x1=expf(l1-mx),x2=expf(l2-mx),x3=expf(l3-mx);
    float x4=expf(l4-mx),x5=expf(l5-mx),x6=expf(l6-mx),x7=expf(l7-mx);
    float inv=1.f/(x0+x1+x2+x3+x4+x5+x6+x7);
    float4 o0=make_float4(x0*inv,x1*inv,x2*inv,x3*inv);
    float4 o1=make_float4(x4*inv,x5*inv,x6*inv,x7*inv);
    const float4* cr=(const float4*)(cur+(size_t)i*CMAX);
    float4 c0=cr[0],c1=cr[1];
    dmx=fmaxf(dmx,fabsf(o0.x-c0.x)); dmx=fmaxf(dmx,fabsf(o0.y-c0.y));
    dmx=fmaxf(dmx,fabsf(o0.z-c0.z)); dmx=fmaxf(dmx,fabsf(o0.w-c0.w));
    dmx=fmaxf(dmx,fabsf(o1.x-c1.x)); dmx=fmaxf(dmx,fabsf(o1.y-c1.y));
    dmx=fmaxf(dmx,fabsf(o1.z-c1.z)); dmx=fmaxf(dmx,fabsf(o1.w-c1.w));
    float4* nr=(float4*)(nxt+(size_t)i*CMAX);
    nr[0]=o0; nr[1]=o1;
  }
  #pragma unroll
  for(int s=32;s>=1;s>>=1) dmx=fmaxf(dmx,__shfl_xor(dmx,s,64));
  if(threadIdx.x==0){
    atomicMax(p.gmaxu+t,__float_as_uint(dmx));   // dmx>=0 -> bits monotone
    __threadfence();
    int fin=atomicAdd(&p.meta[5],1);
    if(fin==(int)gridDim.x-1){                   // last block: commit decision
      p.meta[5]=0;
      float mm=__uint_as_float(p.gmaxu[t]);
      if(mm<1e-4f) p.meta[3]=1;                  // freeze: keep old parity
      else         p.meta[4]=par^1;              // advance
    }
  }
}

// ---------- final argmax over query rows ----------
__global__ void k_arg(P p){
  int q=blockIdx.x*blockDim.x+threadIdx.x;
  if(q>=p.Q)return;
  int C=p.meta[0];
  const float* cur=p.meta[4]? p.yB : p.yA;
  float best=cur[(size_t)q*CMAX+0]; int bc=0;
  for(int c=1;c<C;c++){
    float v=cur[(size_t)q*CMAX+c];
    if(v>best){best=v;bc=c;}
  }
  p.outp[q]=bc;
}

// =======================================================================

static void make_layout(char* base,int S,int Q,int D,int BN,long N,
                        const float*fs,const int*ys,const float*fq,
                        int* outp, P* pp, size_t* need){
  size_t off=0;
  auto A=[&](size_t b)->char*{
    size_t o=(off+255)&~(size_t)255; off=o+b; return base+o;
  };
  P p{};
  p.fs=fs;p.ys=ys;p.fq=fq;p.S=S;p.Q=Q;p.D=D;p.BN=BN;p.NMAX=(int)N;
  p.proto=(float*)A(4ul*CMAX*D);
  p.G=(float*)A(4ul*(size_t)BN*BN);
  p.cosq=(float*)A(4ul*(size_t)Q*Q);
  p.cls=(int*)A(4ul*CMAX);
  p.scount=(int*)A(4ul*CMAX);
  p.qcount=(int*)A(4ul*CMAX);
  p.qidx=(int*)A(4ul*CMAX*Q);
  p.kq=(int*)A(4ul*CMAX);
  p.thr=(float*)A(4ul*CMAX);
  p.rowcnt=(int*)A(4ul*CMAX*Q);
  p.rowoff=(int*)A(4ul*CMAX*Q);
  p.paircnt=(int*)A(4ul*CMAX);
  p.basev=(int*)A(4ul*CMAX);
  p.meta=(int*)A(4ul*16);
  p.uv=(int*)A(8ul*N);
  p.rn2=(float*)A(4ul*N);
  p.cand=(int*)A(16ul*N);
  p.nbrs=(int*)A(4ul*KMAX*N);
  p.dnb=(float*)A(4ul*KMAX*N);
  p.wgt=(float*)A(4ul*KMAX*N);
  p.sigma=(float*)A(4ul*N);
  p.indeg=(int*)A(4ul*N);
  p.inoff=(int*)A(4ul*(N+1));
  p.cursor=(int*)A(4ul*N);
  p.insrcU=(int*)A(4ul*KMAX*N);
  p.inwU=(float*)A(4ul*KMAX*N);
  p.indst=(int*)A(4ul*KMAX*N);
  p.inedge=(int2*)A(8ul*KMAX*N);
  p.cosk=(unsigned*)A(4ul*CMAX*(size_t)Q*Q);
  p.gmaxu=(unsigned*)A(4ul*64);
  p.amat=(float*)A(4ul*CMAX*N);
  p.dinv=(float*)A(4ul*N);
  p.dmin=(float*)A(4ul*N);
  p.scalev=(float*)A(4ul*N);
  p.yA=(float*)A(4ul*CMAX*N);
  p.yB=(float*)A(4ul*CMAX*N);
  p.meddenom=(float*)A(4ul*4);
  p.outp=outp;
  *pp=p; *need=off;
}

extern "C" void kernel_launch(void* const* d_in, const int* in_sizes, int n_in,
                              void* d_out, int out_size, void* d_ws, size_t ws_size,
                              hipStream_t stream){
  const float* fs=(const float*)d_in[0];
  const int*   ys=(const int*)d_in[1];
  const float* fq=(const float*)d_in[2];
  int S=in_sizes[1];
  int D=in_sizes[0]/S;
  int Q=in_sizes[2]/D;
  int BN=Q+CMAX;

  long full=(long)Q + (long)Q*(Q-1)/2 + CMAX;
  long cand[4]={full,16384,8192,5000};
  P p{}; size_t need=0; int NMAX=(int)cand[3];
  for(int ci=0;ci<4;ci++){
    long N=cand[ci]; if(N<Q+CMAX)N=Q+CMAX;
    make_layout((char*)d_ws,S,Q,D,BN,N,fs,ys,fq,(int*)d_out,&p,&need);
    NMAX=(int)N;
    if(need<=ws_size) break;
  }

  int gN=(NMAX+TPB-1)/TPB;
  long gEl=((long)NMAX*KMAX+TPB-1)/TPB;
  int gE=(int)gEl;
  int gS=(NMAX+63)/64;

  k_init   <<<1, 64, 0, stream>>>(p);
  k_proto  <<<CMAX, TPB, 0, stream>>>(p);
  k_gram   <<<BN, TPB, 0, stream>>>(p);
  k_cos    <<<(Q*Q+TPB-1)/TPB, TPB, 0, stream>>>(p);
  k_qidx   <<<CMAX, 64, 0, stream>>>(p);
  k_median <<<CMAX, TPB, 0, stream>>>(p);
  k_rowcnt <<<CMAX, TPB, 0, stream>>>(p);
  k_bases  <<<1, 1, 0, stream>>>(p);
  k_uv     <<<gN, TPB, 0, stream>>>(p);
  k_uvpairs<<<CMAX, TPB, 0, stream>>>(p);
  k_rn2c   <<<gN, TPB, 0, stream>>>(p);
  k_knn    <<<NMAX, 128, 0, stream>>>(p);
  k_wgtcnt <<<gN, TPB, 0, stream>>>(p);
  k_scan   <<<1, TPB, 0, stream>>>(p);
  k_fill   <<<gN, TPB, 0, stream>>>(p);
  k_rank   <<<gE, TPB, 0, stream>>>(p);
  k_dad    <<<gN, TPB, 0, stream>>>(p);
  k_medd   <<<1, TPB, 0, stream>>>(p);
  k_y0     <<<gN, TPB, 0, stream>>>(p);
  for(int t=0;t<50;t++)
    k_step <<<gS, 64, 0, stream>>>(p, t);
  k_arg    <<<(Q+TPB-1)/TPB, TPB, 0, stream>>>(p);
}